// Round 11
// baseline (286.717 us; speedup 1.0000x reference)
//
#include <hip/hip_runtime.h>

#define MM 32
#define LH 128
#define NSTEPS 15          // K-1
#define SSTR 136
#define NBLK 256           // one block per row-pair-of-chains (2 single-row chains)
#define FSTR 32
#define FBASE 4
#define SIDX2(slot,pxi,ch) (((slot)*34 + (pxi))*SSTR + (ch))

typedef __bf16  bf16x8  __attribute__((ext_vector_type(8)));
typedef float   floatx4 __attribute__((ext_vector_type(4)));
typedef unsigned long long ull;

__device__ __forceinline__ float sigm(float x){ return 1.f/(1.f+__expf(-x)); }
__device__ __forceinline__ float tanh_f(float x){ return 1.f - 2.f/(__expf(2.f*x)+1.f); }

__device__ __forceinline__ unsigned short f2bf(float x){
  union { float f; unsigned u; } v; v.f = x;
  unsigned r = v.u + 0x7FFFu + ((v.u >> 16) & 1u);   // RNE
  return (unsigned short)(r >> 16);
}
__device__ __forceinline__ float bf2f(unsigned short u){
  union { unsigned u2; float f; } v; v.u2 = ((unsigned)u) << 16;
  return v.f;
}

__device__ __forceinline__ void st_dev(ull* p, ull v){
  __hip_atomic_store(p, v, __ATOMIC_RELAXED, __HIP_MEMORY_SCOPE_AGENT);
}
__device__ __forceinline__ ull ld_dev(const ull* p){
  return __hip_atomic_load((ull*)p, __ATOMIC_RELAXED, __HIP_MEMORY_SCOPE_AGENT);
}
__device__ __forceinline__ void st_flag(int* f, int v){
  __hip_atomic_store(f, v, __ATOMIC_RELAXED, __HIP_MEMORY_SCOPE_AGENT);
}
__device__ __forceinline__ int ld_flag(int* f){
  return __hip_atomic_load(f, __ATOMIC_RELAXED, __HIP_MEMORY_SCOPE_AGENT);
}
__device__ __forceinline__ void wait_flag(int* f, int target){
  while ((int)(ld_flag(f) - target) < 0) __builtin_amdgcn_s_sleep(1);
}

// h exchange buffers: [global_row][ch][px4] b64 chunks: idx = g*1024 + ch*8 + px4
__global__ __launch_bounds__(512, 2) void k_mega(
    const float* __restrict__ mp,   const float* __restrict__ gl,
    const float* __restrict__ W_hid,const float* __restrict__ b_hid,
    const float* __restrict__ W_h0, const float* __restrict__ b_h0,
    const float* __restrict__ W_c0, const float* __restrict__ b_c0,
    const float* __restrict__ Wf,   const float* __restrict__ bfs,
    const float* __restrict__ wih,  const float* __restrict__ bih,
    const float* __restrict__ Whh,  const float* __restrict__ bhh,
    const float* __restrict__ wpol,
    unsigned short* __restrict__ hA, unsigned short* __restrict__ hB,
    unsigned short* __restrict__ hidb,
    unsigned short* __restrict__ wc0, unsigned short* __restrict__ wc1,
    unsigned short* __restrict__ whhf, float* __restrict__ bsum,
    unsigned short* __restrict__ wfbF,
    int* __restrict__ flags, int* __restrict__ sflags, float* __restrict__ out)
{
  __shared__ __attribute__((aligned(16))) unsigned short sH[6*34*SSTR]; // 55.5 KB
  __shared__ float sInp[2][32];
  __shared__ int sCnt[2];

  int t = threadIdx.x, blk = blockIdx.x;
  int gA = blk, gB = blk + 256;
  int y = blk & 31;                 // same y for both chains
  bool hasU = (y != 0), hasD = (y != 31);
  int wave = t >> 6, l = t & 63, m16 = l & 15, quad = l >> 4;
  int ch = wave*16 + m16;

  if (t == 0){ sCnt[0] = 0; sCnt[1] = 0; }

  // ---- phase P: weight prep into fragment-linear bf16 -------------------
  for (int c = blk*512 + t; c < 91904; c += NBLK*512){
    if (c < 73728){
      int which = (c >= 36864) ? 1 : 0;
      int cc = which ? c - 36864 : c;
      int i2 = cc*4, frag = i2 >> 9, rem = i2 & 511, ll = rem >> 3, e0 = rem & 7;
      int kk = frag >> 5, ct = (frag >> 2) & 7, kc = frag & 3;
      int co = ct*16 + (ll & 15), ci0 = kc*32 + ((ll >> 4) << 3) + e0;
      const float* src = which ? W_c0 : W_h0;
      ull v = 0;
      #pragma unroll
      for (int j=0;j<4;j++) v |= (ull)f2bf(src[(kk<<14) + (ci0+j)*128 + co]) << (16*j);
      st_dev((ull*)(which ? wc1 : wc0) + cc, v);
    } else if (c < 90112){
      int cc = c - 73728;
      int i2 = cc*4, frag = i2 >> 9, rem = i2 & 511, ll = rem >> 3, e0 = rem & 7;
      int q = frag >> 5, ct = (frag >> 2) & 7, kc = frag & 3;
      int rw = q*128 + ct*16 + (ll & 15), col = kc*32 + ((ll >> 4) << 3) + e0;
      const float* s4 = Whh + rw*128 + col;
      ull v = 0;
      #pragma unroll
      for (int j=0;j<4;j++) v |= (ull)f2bf(s4[j]) << (16*j);
      st_dev((ull*)whhf + cc, v);
    } else if (c < 90368){
      int cc = c - 90112; int j = cc*2;
      union { float f[2]; ull u; } pv;
      pv.f[0] = bih[j] + bhh[j]; pv.f[1] = bih[j+1] + bhh[j+1];
      st_dev((ull*)bsum + cc, pv.u);
    } else {
      int cc = c - 90368;
      int i2 = cc*4, frag = i2 >> 9, rem = i2 & 511, ll = rem >> 3, e0 = rem & 7;
      int ky = frag >> 2, kc = frag & 3;
      int n = ll & 15, k0 = kc*32 + ((ll >> 4) << 3) + e0;
      ull v = 0;
      if (n < 3){
        #pragma unroll
        for (int j=0;j<4;j++) v |= (ull)f2bf(Wf[(ky*3 + n)*128 + k0 + j]) << (16*j);
      }
      st_dev((ull*)wfbF + cc, v);
    }
  }

  // ---- phase H: hid for rows gA,gB -> LDS linear temp -------------------
  {
    int hch = t & 127, gidx = t >> 7;   // 0..3
    int c2 = gidx >> 1, xh = (gidx & 1)*16;
    int g = c2 ? gB : gA;
    int bb = g >> 5;
    for (int i = 0; i < 16; i++){
      int x = xh + i;
      float acc = b_hid[hch];
      #pragma unroll
      for (int ky=0; ky<3; ky++){
        int yy = y + ky - 1; if (yy < 0 || yy >= MM) continue;
        #pragma unroll
        for (int kx=0; kx<3; kx++){
          int xx = x + kx - 1; if (xx < 0 || xx >= MM) continue;
          int gi = (bb*MM + yy)*MM + xx;
          int wb = ((ky*3+kx)*2)*LH + hch;
          acc += mp[gi] * W_hid[wb] + gl[gi] * W_hid[wb + LH];
        }
      }
      sH[(c2*32 + x)*128 + hch] = f2bf(acc);
    }
  }
  __syncthreads();
  #pragma unroll
  for (int j=0;j<4;j++){                 // publish hid: [g][px][c4]
    int chunk = j*512 + t;
    int g = (chunk >> 10) ? gB : gA;
    int w = chunk & 1023;
    st_dev((ull*)hidb + (size_t)g*1024 + w, *(ull*)&sH[chunk*4]);
  }
  __syncthreads();
  if (t == 0) st_flag(&flags[blk*FSTR], 1);
  if (t < NBLK) wait_flag(&flags[t*FSTR], 1);
  __syncthreads();

  // ---- stage 6 hid rows (3 per chain, halo-padded) ----------------------
  #pragma unroll
  for (int jj=0; jj<12; jj++){
    int cc = jj*512 + t;                 // 6144 chunks
    int slot = cc >> 10;                 // 0..5
    int c2 = slot / 3, k = slot - c2*3;
    int g = (c2 ? gB : gA) + k - 1;
    bool ok = (k == 1) || (k == 0 ? hasU : hasD);
    int w = cc & 1023, px = w >> 5, c4 = w & 31;
    ull v = ok ? ld_dev((const ull*)hidb + (size_t)g*1024 + w) : 0;
    *(ull*)&sH[SIDX2(slot, px+1, c4*4)] = v;
  }
  if (t < 384){                          // zero pad columns of all 6 slots
    int slot = t >> 6, col = ((t >> 5) & 1) ? 33 : 0, c4 = t & 31;
    *(ull*)&sH[SIDX2(slot, col, c4*4)] = 0;
  }
  __syncthreads();

  // ---- h0/c0 convs for both chains --------------------------------------
  float c_reg[2][2][4];                  // [chain][mt][r]
  {
    floatx4 acch[2][2], accc[2][2];
    #pragma unroll
    for (int c2=0;c2<2;c2++)
      #pragma unroll
      for (int mt=0;mt<2;mt++){ acch[c2][mt] = (floatx4){0.f,0.f,0.f,0.f};
                                accc[c2][mt] = (floatx4){0.f,0.f,0.f,0.f}; }
    #pragma unroll
    for (int kk=0; kk<9; kk++){
      int ky = kk/3, kx = kk%3;
      #pragma unroll
      for (int kc=0; kc<4; kc++){
        int frag = ((kk*8 + wave)*4 + kc);
        bf16x8 b0 = *(const bf16x8*)(wc0 + (frag << 9) + l*8);
        bf16x8 b1 = *(const bf16x8*)(wc1 + (frag << 9) + l*8);
        #pragma unroll
        for (int c2=0;c2<2;c2++)
          #pragma unroll
          for (int mt=0; mt<2; mt++){
            bf16x8 a = *(const bf16x8*)&sH[SIDX2(c2*3 + ky, mt*16 + m16 + kx, kc*32 + quad*8)];
            acch[c2][mt] = __builtin_amdgcn_mfma_f32_16x16x32_bf16(a, b0, acch[c2][mt], 0,0,0);
            accc[c2][mt] = __builtin_amdgcn_mfma_f32_16x16x32_bf16(a, b1, accc[c2][mt], 0,0,0);
          }
      }
    }
    __syncthreads();                     // conv reads done
    float bh = b_h0[ch], bc = b_c0[ch];
    #pragma unroll
    for (int c2=0;c2<2;c2++){
      int g = c2 ? gB : gA;
      #pragma unroll
      for (int mt=0; mt<2; mt++){
        ull pack = 0;
        #pragma unroll
        for (int r=0; r<4; r++){
          int px = mt*16 + quad*4 + r;
          c_reg[c2][mt][r] = accc[c2][mt][r] + bc;
          unsigned short hbf = f2bf(acch[c2][mt][r] + bh);
          sH[SIDX2(c2*3+1, px+1, ch)] = hbf;
          pack |= (ull)hbf << (16*r);
        }
        st_dev((ull*)hA + (size_t)g*1024 + ch*8 + mt*4 + quad, pack);
      }
    }
    asm volatile("s_waitcnt vmcnt(0)" ::: "memory");
    if (l == 0){
      int oldA = atomicAdd(&sCnt[0], 1); if (oldA == 7) st_flag(&sflags[gA*FSTR], FBASE);
      int oldB = atomicAdd(&sCnt[1], 1); if (oldB == 7) st_flag(&sflags[gB*FSTR], FBASE);
    }
  }
  // edge halo slots stay zero forever (land skips them)
  if (!hasU){
    #pragma unroll
    for (int jj=0;jj<2;jj++){
      int idx = jj*512 + t; int px = idx >> 5, c8 = idx & 31;
      *(ull*)&sH[SIDX2(0, px+1, c8*4)] = 0;
      *(ull*)&sH[SIDX2(3, px+1, c8*4)] = 0;
    }
  }
  if (!hasD){
    #pragma unroll
    for (int jj=0;jj<2;jj++){
      int idx = jj*512 + t; int px = idx >> 5, c8 = idx & 31;
      *(ull*)&sH[SIDX2(2, px+1, c8*4)] = 0;
      *(ull*)&sH[SIDX2(5, px+1, c8*4)] = 0;
    }
  }

  // W_hh^T fragments + wf fragments + epilogue consts ---------------------
  bf16x8 bfr[4][4];
  #pragma unroll
  for (int q=0;q<4;q++)
    #pragma unroll
    for (int kc=0;kc<4;kc++)
      bfr[q][kc] = *(const bf16x8*)(whhf + ((((q*8 + wave)*4 + kc)) << 9) + l*8);
  int tl = wave & 1, kcw = wave >> 1;
  bf16x8 wfBr[3];
  #pragma unroll
  for (int ky=0;ky<3;ky++)
    wfBr[ky] = *(const bf16x8*)(wfbF + (((ky*4 + kcw) << 9) + l*8));
  float wv[4], bs[4];
  #pragma unroll
  for (int q=0;q<4;q++){ int g2 = q*128 + ch; wv[q] = wih[g2]; bs[q] = bsum[g2]; }
  float bf0 = bfs[0];
  unsigned short* hb[2] = {hA, hB};

  // poll helper (all threads poll both neighbor flags of row g)
  #define POLL_ROW(g, need) do {                                             \
    int fu_ok = hasU ? 0 : 1, fd_ok = hasD ? 0 : 1;                          \
    while (!(fu_ok & fd_ok)){                                                \
      if (!fu_ok && (int)(ld_flag(&sflags[((g)-1)*FSTR]) - (need)) >= 0) fu_ok = 1; \
      if (!fd_ok && (int)(ld_flag(&sflags[((g)+1)*FSTR]) - (need)) >= 0) fd_ok = 1; \
      if (!(fu_ok & fd_ok)) __builtin_amdgcn_s_sleep(1);                     \
    }                                                                        \
    asm volatile("" ::: "memory");                                           \
  } while(0)

  #define ISSUE_HALO(hv, g, buf) do {                                        \
    _Pragma("unroll")                                                        \
    for (int j=0;j<4;j++){                                                   \
      int cc2 = j*512 + t, rsel = cc2 >> 10, w2 = cc2 & 1023;                \
      bool ok2 = rsel ? hasD : hasU;                                         \
      hv[j] = ok2 ? ld_dev((const ull*)(buf) + (size_t)((g) + (rsel?1:-1))*1024 + w2) : 0; \
    }                                                                        \
  } while(0)

  ull hvA[4], hvB[4];
  POLL_ROW(gA, FBASE); ISSUE_HALO(hvA, gA, hb[0]);
  POLL_ROW(gB, FBASE); ISSUE_HALO(hvB, gB, hb[0]);

  // ---- 15 steps, two interleaved chains ---------------------------------
  for (int i = 1; i <= NSTEPS; i++){
    #pragma unroll
    for (int c2 = 0; c2 < 2; c2++){
      int g = c2 ? gB : gA;
      int base = c2*3;
      ull* hv = c2 ? hvB : hvA;
      // land halos (rows base+0, base+2) + init sInp
      if (t < 32) sInp[c2][t] = bf0;
      #pragma unroll
      for (int j=0;j<4;j++){
        int cc2 = j*512 + t, rsel = cc2 >> 10, w2 = cc2 & 1023;
        bool ok2 = rsel ? hasD : hasU;
        if (ok2){
          int ch2 = w2 >> 3, px4 = w2 & 7;
          int slot = base + (rsel ? 2 : 0);
          #pragma unroll
          for (int k2=0;k2<4;k2++)
            sH[SIDX2(slot, px4*4+1+k2, ch2)] = (unsigned short)(hv[j] >> (16*k2));
        }
      }
      __syncthreads();                   // halos + sInp init visible

      // gates GEMM on own row (slot base+1)
      floatx4 acc[2][4];
      #pragma unroll
      for (int mt=0;mt<2;mt++)
        #pragma unroll
        for (int q=0;q<4;q++) acc[mt][q] = (floatx4){0.f,0.f,0.f,0.f};
      #pragma unroll
      for (int kc=0; kc<4; kc++){
        bf16x8 a0 = *(const bf16x8*)&sH[SIDX2(base+1, m16 + 1,  kc*32 + quad*8)];
        bf16x8 a1 = *(const bf16x8*)&sH[SIDX2(base+1, m16 + 17, kc*32 + quad*8)];
        #pragma unroll
        for (int q=0; q<4; q++){
          acc[0][q] = __builtin_amdgcn_mfma_f32_16x16x32_bf16(a0, bfr[q][kc], acc[0][q], 0,0,0);
          acc[1][q] = __builtin_amdgcn_mfma_f32_16x16x32_bf16(a1, bfr[q][kc], acc[1][q], 0,0,0);
        }
      }
      // wf conv via MFMA (wave = (tile tl, kc kcw)); correlation: dx = 1-kx
      {
        floatx4 pacc = (floatx4){0.f,0.f,0.f,0.f};
        #pragma unroll
        for (int ky=0; ky<3; ky++){
          bf16x8 a = *(const bf16x8*)&sH[SIDX2(base+ky, tl*16 + m16 + 1, kcw*32 + quad*8)];
          pacc = __builtin_amdgcn_mfma_f32_16x16x32_bf16(a, wfBr[ky], pacc, 0,0,0);
        }
        if (m16 < 3){
          int dx = 1 - m16;
          #pragma unroll
          for (int r=0; r<4; r++){
            int px = tl*16 + quad*4 + r;
            int xt = px + dx;
            if (xt >= 0 && xt < 32) atomicAdd(&sInp[c2][xt], pacc[r]);
          }
        }
      }
      __syncthreads();                   // sInp complete, own-row reads done

      // epilogue: h_{i} -> LDS + register-direct publish
      #pragma unroll
      for (int mt=0; mt<2; mt++){
        ull pack = 0;
        #pragma unroll
        for (int r=0; r<4; r++){
          int px = mt*16 + quad*4 + r;
          float iv = sInp[c2][px];
          float pre0 = acc[mt][0][r] + iv*wv[0] + bs[0];
          float pre1 = acc[mt][1][r] + iv*wv[1] + bs[1];
          float pre2 = acc[mt][2][r] + iv*wv[2] + bs[2];
          float pre3 = acc[mt][3][r] + iv*wv[3] + bs[3];
          float ig = sigm(pre0), fg = sigm(pre1), gg = tanh_f(pre2), og = sigm(pre3);
          float cn = fg*c_reg[c2][mt][r] + ig*gg;
          c_reg[c2][mt][r] = cn;
          unsigned short hbf = f2bf(og * tanh_f(cn));
          sH[SIDX2(base+1, px+1, ch)] = hbf;
          pack |= (ull)hbf << (16*r);
        }
        if (i < NSTEPS)
          st_dev((ull*)hb[i&1] + (size_t)g*1024 + ch*8 + mt*4 + quad, pack);
      }
      if (i < NSTEPS){
        asm volatile("s_waitcnt vmcnt(0)" ::: "memory");
        if (l == 0){
          int old = atomicAdd(&sCnt[c2], 1);
          if (old == 8*i + 7) st_flag(&sflags[g*FSTR], FBASE + i);
        }
        // tail: prefetch this chain's next halo (RT covered by other phase)
        POLL_ROW(g, FBASE + i);
        ISSUE_HALO(hv, g, hb[i&1]);
      }
    }
  }
  __syncthreads();

  // ---- policy: logits + 4-way softmax (both chains) ---------------------
  {
    int px64 = t >> 3, s8 = t & 7;
    int c2 = px64 >> 5, x = px64 & 31;
    int g = c2 ? gB : gA;
    int bb = g >> 5;
    int base2 = SIDX2(c2*3+1, x+1, s8*16);
    uint4 h0v = *(const uint4*)&sH[base2];
    uint4 h1v = *(const uint4*)&sH[base2 + 8];
    float la[4] = {0.f,0.f,0.f,0.f};
    const unsigned short* hu = (const unsigned short*)&h0v;
    #pragma unroll
    for (int e=0;e<8;e++){
      int c = s8*16 + e; float hv2 = bf2f(hu[e]);
      const float* w4 = wpol + c*4;
      la[0]+=hv2*w4[0]; la[1]+=hv2*w4[1]; la[2]+=hv2*w4[2]; la[3]+=hv2*w4[3];
    }
    hu = (const unsigned short*)&h1v;
    #pragma unroll
    for (int e=0;e<8;e++){
      int c = s8*16 + 8 + e; float hv2 = bf2f(hu[e]);
      const float* w4 = wpol + c*4;
      la[0]+=hv2*w4[0]; la[1]+=hv2*w4[1]; la[2]+=hv2*w4[2]; la[3]+=hv2*w4[3];
    }
    #pragma unroll
    for (int a=0;a<4;a++){
      la[a] += __shfl_xor(la[a], 1, 64);
      la[a] += __shfl_xor(la[a], 2, 64);
      la[a] += __shfl_xor(la[a], 4, 64);
    }
    if (s8 == 0){
      float m = fmaxf(fmaxf(la[0],la[1]),fmaxf(la[2],la[3]));
      float e[4]; float sum = 0.f;
      #pragma unroll
      for (int a=0;a<4;a++){ e[a]=__expf(la[a]-m); sum+=e[a]; }
      float inv = 1.f/sum;
      #pragma unroll
      for (int a=0;a<4;a++){
        int o = ((bb*4 + a)*MM + y)*MM + x;
        out[o] = la[a];
        out[65536 + o] = e[a]*inv;
      }
    }
  }
}

extern "C" void kernel_launch(void* const* d_in, const int* in_sizes, int n_in,
                              void* d_out, int out_size, void* d_ws, size_t ws_size,
                              hipStream_t stream){
  const float* mp    = (const float*)d_in[0];
  const float* gl    = (const float*)d_in[1];
  const float* W_hid = (const float*)d_in[2];
  const float* b_hid = (const float*)d_in[3];
  const float* W_h0  = (const float*)d_in[4];
  const float* b_h0  = (const float*)d_in[5];
  const float* W_c0  = (const float*)d_in[6];
  const float* b_c0  = (const float*)d_in[7];
  const float* W_f   = (const float*)d_in[8];
  const float* b_f   = (const float*)d_in[9];
  const float* W_ih  = (const float*)d_in[10];
  const float* b_ih  = (const float*)d_in[11];
  const float* W_hh  = (const float*)d_in[12];
  const float* b_hh  = (const float*)d_in[13];
  const float* W_pol = (const float*)d_in[14];
  float* out = (float*)d_out;

  char* ws = (char*)d_ws;
  unsigned short* hA    = (unsigned short*)ws;                          // 4 MB
  unsigned short* hB    = (unsigned short*)(ws + ((size_t) 4<<20));     // 4 MB
  unsigned short* hidb  = (unsigned short*)(ws + ((size_t) 8<<20));     // 4 MB
  unsigned short* whhf  = (unsigned short*)(ws + ((size_t)12<<20));     // 128 KB
  float*          bsum  = (float*)(ws + ((size_t)12<<20) + (128<<10));  // 4 KB
  unsigned short* wc0   = (unsigned short*)(ws + ((size_t)12<<20) + (132<<10)); // 288 KB
  unsigned short* wc1   = (unsigned short*)(ws + ((size_t)12<<20) + (420<<10)); // 288 KB
  int*            flags = (int*)(ws + ((size_t)12<<20) + (708<<10));    // 32 KB
  unsigned short* wfbF  = (unsigned short*)(ws + ((size_t)12<<20) + (740<<10)); // 12 KB
  int*            sflags= (int*)(ws + ((size_t)12<<20) + (752<<10));    // 64 KB

  k_mega<<<NBLK, 512, 0, stream>>>(
      mp, gl, W_hid, b_hid, W_h0, b_h0, W_c0, b_c0, W_f, b_f,
      W_ih, b_ih, W_hh, b_hh, W_pol,
      hA, hB, hidb, wc0, wc1, whhf, bsum, wfbF, flags, sflags, out);
}